// Round 14
// baseline (78.966 us; speedup 1.0000x reference)
//
#include <hip/hip_runtime.h>

// Caps_BN: BatchNorm2d (training stats, affine=False) + grouped 1x1 conv
// (16 capsules of 32x32) + bias, folded: out = W''@x + b',
//   W'' = bf16(W * rstd),  b' = bias - (W*rstd) @ mean   (fp32, exact via C operand)
// x (64, 512, 32, 32) f32.
//
// R13 diagnosis: main is VALU-ISSUE-bound (~35us of VALU-busy vs 21us write
// floor; R1 measured 50% VALUBusy, and the R5 pure-ILP fix moved -25us while
// traffic was constant; three memory-shape variants all landed ~50us). fp32 has
// no MFMA, so this round moves the 1024 FMAs/thread to the matrix pipe via
// mfma_f32_16x16x32_bf16 (full K=32 in one op). bf16 error budget ~0.03-0.06
// vs threshold 0.1106.
//
// Fragment layouts: C/D col=lane&15, row=(lane>>4)*4+e  [m89-verified];
// A row=lane&15, k=8*(lane>>4)+e; B col=lane&15, k=8*(lane>>4)+e.
// Fold stores W'' bf16 row-major [o][i] so A-frags are two 16B loads.
//
// ws layout (floats):
//   [0, 512)       mean per channel
//   [512, 1024)    rstd per channel
//   [1024, 9216)   W'' bf16 (c, o, i) as ushort[16][1024]
//   [9216, 9728)   b' fp32 (c, o)
//
// Standing lessons: 3-kernel structure (fusion abandoned: R8 capture-unsafe
// grid.sync, R9 atomic-poll storm, R11 spill, R12 s_load loss). NEVER set
// launch_bounds min-waves (R4/R6 spills). Scalar 4B/lane stores = the only
// 1.0x-WRITE pattern; nt stores protect L3-resident x.

#define NELEM_PER_CH 65536.0f
#define WS_WB   1024
#define WS_BP   9216

typedef __attribute__((ext_vector_type(8))) short bf16x8;
typedef __attribute__((ext_vector_type(4))) float f32x4;
typedef __attribute__((ext_vector_type(4))) int int4v;

__global__ __launch_bounds__(256) void caps_stats(const float* __restrict__ x,
                                                  float* __restrict__ ws) {
    const int ch = blockIdx.x;      // 0..511
    const int tid = threadIdx.x;    // 0..255
    const float4* __restrict__ x4 = (const float4*)x;

    float s = 0.f, ss = 0.f;
#pragma unroll 4
    for (int n = 0; n < 64; ++n) {
        float4 v = x4[((size_t)n * 512 + ch) * 256 + tid];
        s  += v.x + v.y + v.z + v.w;
        ss += v.x * v.x + v.y * v.y + v.z * v.z + v.w * v.w;
    }
#pragma unroll
    for (int off = 32; off > 0; off >>= 1) {
        s  += __shfl_down(s, off);
        ss += __shfl_down(ss, off);
    }
    __shared__ float red[4][2];
    if ((tid & 63) == 0) { red[tid >> 6][0] = s; red[tid >> 6][1] = ss; }
    __syncthreads();
    if (tid == 0) {
        float S = 0.f, SS = 0.f;
#pragma unroll
        for (int k = 0; k < 4; ++k) { S += red[k][0]; SS += red[k][1]; }
        float mean = S / NELEM_PER_CH;
        float var = SS / NELEM_PER_CH - mean * mean;
        ws[ch] = mean;
        ws[512 + ch] = rsqrtf(var + 1e-5f);
    }
}

// 16 blocks x 1024 threads; t = o*32+i. Emits W'' bf16 (RNE) + b' fp32.
__global__ __launch_bounds__(1024) void caps_fold(const float* __restrict__ w,
                                                  const float* __restrict__ bias,
                                                  float* __restrict__ ws) {
    const int c = blockIdx.x;
    const int t = threadIdx.x;
    const int o = t >> 5;
    const int i = t & 31;
    const float mean = ws[c * 32 + i];
    const float rstd = ws[512 + c * 32 + i];
    const float wv = w[c * 1024 + t] * rstd;

    // fp32 -> bf16 round-to-nearest-even (values are normal floats)
    unsigned u = __builtin_bit_cast(unsigned, wv);
    unsigned r = (u + 0x7FFFu + ((u >> 16) & 1u)) >> 16;
    ((ushort*)(ws + WS_WB))[c * 1024 + t] = (ushort)r;

    float prod = wv * mean;
#pragma unroll
    for (int off = 16; off > 0; off >>= 1) prod += __shfl_xor(prod, off);
    if (i == 0) ws[WS_BP + c * 32 + o] = bias[c * 32 + o] - prod;
}

// Main: grid (16, 64) = (c, n); block 256 = 4 waves. Wave wid handles 16
// hw-strips of 16 columns; per strip: B-frag from 8 scalar x loads + cvt_pk,
// two MFMAs (o rows 0-15 and 16-31, K=32 in one op), bias via C operand,
// 8 scalar nt stores per lane.
__global__ __launch_bounds__(256) void caps_main(const float* __restrict__ x,
                                                 const float* __restrict__ ws,
                                                 float* __restrict__ out) {
    const int c = blockIdx.x;
    const int n = blockIdx.y;
    const int t = threadIdx.x;
    const int l = t & 63;          // lane
    const int wid = t >> 6;        // wave 0..3
    const int cl = l & 15;         // B col / A row / C col
    const int g = l >> 4;          // lane group 0..3: k = 8g..8g+7, C rows g*4+e

    const int tile = ((n * 16 + c) * 32) * 1024;
    const ushort* __restrict__ wb = (const ushort*)(ws + WS_WB) + c * 1024;
    const float* __restrict__ bp = ws + WS_BP + c * 32;

    const bf16x8 a_lo = *(const bf16x8*)(wb + cl * 32 + g * 8);          // rows 0-15
    const bf16x8 a_hi = *(const bf16x8*)(wb + (16 + cl) * 32 + g * 8);   // rows 16-31

    f32x4 ci_lo, ci_hi;            // bias pre-loaded into the accumulator
#pragma unroll
    for (int e = 0; e < 4; ++e) {
        ci_lo[e] = bp[g * 4 + e];
        ci_hi[e] = bp[16 + g * 4 + e];
    }

    const float* __restrict__ xg = x + tile + g * 8 * 1024 + cl;
    float* __restrict__ og = out + tile + cl;

#pragma unroll 2
    for (int k = 0; k < 16; ++k) {
        const int sb = (wid * 16 + k) * 16;         // strip column base
        const float v0 = xg[sb];
        const float v1 = xg[sb + 1024];
        const float v2 = xg[sb + 2048];
        const float v3 = xg[sb + 3072];
        const float v4 = xg[sb + 4096];
        const float v5 = xg[sb + 5120];
        const float v6 = xg[sb + 6144];
        const float v7 = xg[sb + 7168];
        int d0, d1, d2, d3;
        asm("v_cvt_pk_bf16_f32 %0, %1, %2" : "=v"(d0) : "v"(v0), "v"(v1));
        asm("v_cvt_pk_bf16_f32 %0, %1, %2" : "=v"(d1) : "v"(v2), "v"(v3));
        asm("v_cvt_pk_bf16_f32 %0, %1, %2" : "=v"(d2) : "v"(v4), "v"(v5));
        asm("v_cvt_pk_bf16_f32 %0, %1, %2" : "=v"(d3) : "v"(v6), "v"(v7));
        const int4v bi = {d0, d1, d2, d3};
        const bf16x8 bfr = __builtin_bit_cast(bf16x8, bi);

        const f32x4 accl = __builtin_amdgcn_mfma_f32_16x16x32_bf16(a_lo, bfr, ci_lo, 0, 0, 0);
        const f32x4 acch = __builtin_amdgcn_mfma_f32_16x16x32_bf16(a_hi, bfr, ci_hi, 0, 0, 0);

#pragma unroll
        for (int e = 0; e < 4; ++e) {
            __builtin_nontemporal_store(accl[e], og + sb + (g * 4 + e) * 1024);
            __builtin_nontemporal_store(acch[e], og + sb + (16 + g * 4 + e) * 1024);
        }
    }
}

extern "C" void kernel_launch(void* const* d_in, const int* in_sizes, int n_in,
                              void* d_out, int out_size, void* d_ws, size_t ws_size,
                              hipStream_t stream) {
    const float* x    = (const float*)d_in[0];
    const float* w    = (const float*)d_in[1];
    const float* bias = (const float*)d_in[2];
    float* out = (float*)d_out;
    float* ws  = (float*)d_ws;

    caps_stats<<<512, 256, 0, stream>>>(x, ws);
    caps_fold<<<16, 1024, 0, stream>>>(w, bias, ws);
    caps_main<<<dim3(16, 64), 256, 0, stream>>>(x, ws, out);
}